// Round 8
// baseline (16.968 us; speedup 1.0000x reference)
//
#include <hip/hip_runtime.h>

#define BB     128
#define CCH    2048
#define NRODT  512
#define NEST   128
#define NF     100
#define NHID   128
#define BT     32      // batch rows per forest block
#define TPB    512

typedef __attribute__((ext_vector_type(8))) short short8v;
typedef __attribute__((ext_vector_type(4))) float f32x4;

static __device__ __forceinline__ unsigned short f2bf(float x) {
    unsigned u = __float_as_uint(x);
    u += 0x7FFFu + ((u >> 16) & 1u);   // RNE
    return (unsigned short)(u >> 16);
}
static __device__ __forceinline__ float bf2f(unsigned short h) {
    return __uint_as_float(((unsigned)h) << 16);
}

// ---------------------------------------------------------------------------
// Kernel 1: (a) per-(b,g) phi_2 pipeline -> wbuf[g*BB+b] (transposed), and
// (b) one E element per thread converted to packed {hi,lo} bf16 (Esp).
// ---------------------------------------------------------------------------
__global__ __launch_bounds__(256) void phi2_kernel(
    const float* __restrict__ O,
    const float* __restrict__ g1w, const float* __restrict__ g1b,
    const float* __restrict__ W1,  const float* __restrict__ b1,
    const float* __restrict__ g2w, const float* __restrict__ g2b,
    const float* __restrict__ W2,  const float* __restrict__ b2,
    const float* __restrict__ E,
    float* __restrict__ wbuf,
    unsigned* __restrict__ Esp)
{
    const int t = blockIdx.x * 256 + threadIdx.x;
    const int b = t >> 9;
    const int g = t & (NRODT - 1);

    // ---- E hi/lo split: one element per thread (65536 == 512*128) ----
    {
        const float ex = E[t];
        const unsigned short xh = f2bf(ex);
        const float r = ex - bf2f(xh);
        const unsigned short xl = f2bf(r);
        Esp[t] = ((unsigned)xh) | (((unsigned)xl) << 16);
    }

    const float4 x = *reinterpret_cast<const float4*>(O + (size_t)b * CCH + g * 4);

    float m  = 0.25f * ((x.x + x.y) + (x.z + x.w));
    float d0 = x.x - m, d1 = x.y - m, d2 = x.z - m, d3 = x.w - m;
    float v  = 0.25f * ((d0 * d0 + d1 * d1) + (d2 * d2 + d3 * d3));
    float iv = rsqrtf(v + 1e-5f);
    const float4 gw1 = *reinterpret_cast<const float4*>(g1w + g * 4);
    const float4 gb1 = *reinterpret_cast<const float4*>(g1b + g * 4);
    float a0 = fmaf(d0 * iv, gw1.x, gb1.x);
    float a1 = fmaf(d1 * iv, gw1.y, gb1.y);
    float a2 = fmaf(d2 * iv, gw1.z, gb1.z);
    float a3 = fmaf(d3 * iv, gw1.w, gb1.w);

    const float4 r0 = *reinterpret_cast<const float4*>(W1 + g * 16 + 0);
    const float4 r1 = *reinterpret_cast<const float4*>(W1 + g * 16 + 4);
    const float4 r2 = *reinterpret_cast<const float4*>(W1 + g * 16 + 8);
    const float4 r3 = *reinterpret_cast<const float4*>(W1 + g * 16 + 12);
    const float4 bc = *reinterpret_cast<const float4*>(b1 + g * 4);
    float y0 = fmaf(a0, r0.x, fmaf(a1, r1.x, fmaf(a2, r2.x, fmaf(a3, r3.x, bc.x))));
    float y1 = fmaf(a0, r0.y, fmaf(a1, r1.y, fmaf(a2, r2.y, fmaf(a3, r3.y, bc.y))));
    float y2 = fmaf(a0, r0.z, fmaf(a1, r1.z, fmaf(a2, r2.z, fmaf(a3, r3.z, bc.z))));
    float y3 = fmaf(a0, r0.w, fmaf(a1, r1.w, fmaf(a2, r2.w, fmaf(a3, r3.w, bc.w))));
    y0 = fmaxf(y0, 0.f); y1 = fmaxf(y1, 0.f); y2 = fmaxf(y2, 0.f); y3 = fmaxf(y3, 0.f);

    m  = 0.25f * ((y0 + y1) + (y2 + y3));
    d0 = y0 - m; d1 = y1 - m; d2 = y2 - m; d3 = y3 - m;
    v  = 0.25f * ((d0 * d0 + d1 * d1) + (d2 * d2 + d3 * d3));
    iv = rsqrtf(v + 1e-5f);
    const float4 gw2 = *reinterpret_cast<const float4*>(g2w + g * 4);
    const float4 gb2 = *reinterpret_cast<const float4*>(g2b + g * 4);
    float z0 = fmaf(d0 * iv, gw2.x, gb2.x);
    float z1 = fmaf(d1 * iv, gw2.y, gb2.y);
    float z2 = fmaf(d2 * iv, gw2.z, gb2.z);
    float z3 = fmaf(d3 * iv, gw2.w, gb2.w);

    const float4 w2 = *reinterpret_cast<const float4*>(W2 + g * 4);
    float res = fmaf(z0, w2.x, fmaf(z1, w2.y, fmaf(z2, w2.z, fmaf(z3, w2.w, b2[g]))));

    wbuf[g * BB + b] = res;   // transposed [NRODT, B]
}

// ---------------------------------------------------------------------------
// Kernel 2: per (f, 32-batch tile). Coalesced wT gather -> softmax -> bf16 P;
// E staged from pre-split packed bf16 (no conversion VALU); MFMA combine.
// ---------------------------------------------------------------------------
__global__ __launch_bounds__(TPB) void forest_mfma_kernel(
    const float*    __restrict__ wv,    // [NRODT, B]  (transposed)
    const unsigned* __restrict__ Esp,   // [NRODT, NHID] packed {hi,lo} bf16
    const int*      __restrict__ swr,   // [NF, NEST]
    float* __restrict__ out)            // [B, NF, NHID]
{
    __shared__ __align__(16) short Prow[BT][136];   // P bf16, row stride 272B
    __shared__ __align__(16) char  pool[2 * 128 * 72 * 2];  // 36864B
    __shared__ int   ids[NEST];
    __shared__ float invs[BT];

    short (*Ehi)[72] = reinterpret_cast<short(*)[72]>(pool);
    short (*Elo)[72] = reinterpret_cast<short(*)[72]>(pool + 128 * 72 * 2);
    float (*wT)[36]  = reinterpret_cast<float(*)[36]>(pool);  // dead after softmax

    const int f   = blockIdx.x;
    const int b0  = blockIdx.y * BT;
    const int tid = threadIdx.x;

    if (tid < NEST) ids[tid] = swr[f * NEST + tid];
    __syncthreads();

    // ---- stage wT[e][b] coalesced: thread (e = tid>>2, j = tid&3) -> 8 b's ----
    {
        const int e = tid >> 2;
        const int j = tid & 3;
        const float* src = wv + (size_t)ids[e] * BB + b0 + (j << 3);
        const float4 va = *reinterpret_cast<const float4*>(src);
        const float4 vb = *reinterpret_cast<const float4*>(src + 4);
        *reinterpret_cast<float4*>(&wT[e][(j << 3) + 0]) = va;
        *reinterpret_cast<float4*>(&wT[e][(j << 3) + 4]) = vb;
    }
    __syncthreads();

    // ---- softmax numerators (f32 from LDS), written to Prow as bf16 ----
    {
        const int bl = tid >> 4;          // 0..31 batch row
        const int jj = tid & 15;
        float val[8];
        float mx = -3.4e38f;
        #pragma unroll
        for (int k = 0; k < 8; ++k) {
            val[k] = wT[jj + (k << 4)][bl];
            mx = fmaxf(mx, val[k]);
        }
        mx = fmaxf(mx, __shfl_xor(mx, 1));
        mx = fmaxf(mx, __shfl_xor(mx, 2));
        mx = fmaxf(mx, __shfl_xor(mx, 4));
        mx = fmaxf(mx, __shfl_xor(mx, 8));
        float sum = 0.f;
        #pragma unroll
        for (int k = 0; k < 8; ++k) {
            float ex = __expf(val[k] - mx);
            sum += ex;
            Prow[bl][jj + (k << 4)] = (short)f2bf(ex);
        }
        sum += __shfl_xor(sum, 1);
        sum += __shfl_xor(sum, 2);
        sum += __shfl_xor(sum, 4);
        sum += __shfl_xor(sum, 8);
        if (jj == 0) invs[bl] = 1.f / sum;
    }
    __syncthreads();   // wT reads done -> pool reusable; Prow/invs visible

    // ---- MFMA setup ----
    const int lane = tid & 63;
    const int wid  = tid >> 6;          // 0..7
    const int rt   = wid & 1;           // row-tile (batch)
    const int ct0  = (wid >> 1) << 1;   // col-tiles ct0, ct0+1 (h)
    const int lm   = lane & 15;
    const int lk   = (lane >> 4) << 3;  // k-offset within 32-wide K-block

    f32x4 acc0 = {0.f, 0.f, 0.f, 0.f};
    f32x4 acc1 = {0.f, 0.f, 0.f, 0.f};

    const int h  = tid & 127;           // staging: h column
    const int eg = tid >> 7;            // staging: 16-estimator subgroup

    #pragma unroll
    for (int hf = 0; hf < 2; ++hf) {
        // ---- stage 64 estimator rows of pre-split E, transposed [h][e] ----
        {
            short hbuf[16], lbuf[16];
            #pragma unroll
            for (int i = 0; i < 16; ++i) {
                const int row = ids[hf * 64 + eg * 16 + i];        // wave-uniform
                const unsigned v = Esp[(size_t)row * NHID + h];    // coalesced 256B
                hbuf[i] = (short)(v & 0xFFFFu);
                lbuf[i] = (short)(v >> 16);
            }
            if (hf == 1) __syncthreads();   // prior half's MFMA reads done
            *reinterpret_cast<short8v*>(&Ehi[h][eg * 16 + 0]) = *reinterpret_cast<short8v*>(&hbuf[0]);
            *reinterpret_cast<short8v*>(&Ehi[h][eg * 16 + 8]) = *reinterpret_cast<short8v*>(&hbuf[8]);
            *reinterpret_cast<short8v*>(&Elo[h][eg * 16 + 0]) = *reinterpret_cast<short8v*>(&lbuf[0]);
            *reinterpret_cast<short8v*>(&Elo[h][eg * 16 + 8]) = *reinterpret_cast<short8v*>(&lbuf[8]);
        }
        __syncthreads();

        // ---- 2 K-blocks of 32 within this half ----
        #pragma unroll
        for (int kbl = 0; kbl < 2; ++kbl) {
            const short8v a =
                *reinterpret_cast<const short8v*>(&Prow[rt * 16 + lm][(hf * 2 + kbl) * 32 + lk]);
            const short8v bh0 = *reinterpret_cast<const short8v*>(&Ehi[ct0 * 16 + lm][kbl * 32 + lk]);
            const short8v bl0 = *reinterpret_cast<const short8v*>(&Elo[ct0 * 16 + lm][kbl * 32 + lk]);
            const short8v bh1 = *reinterpret_cast<const short8v*>(&Ehi[(ct0 + 1) * 16 + lm][kbl * 32 + lk]);
            const short8v bl1 = *reinterpret_cast<const short8v*>(&Elo[(ct0 + 1) * 16 + lm][kbl * 32 + lk]);
            acc0 = __builtin_amdgcn_mfma_f32_16x16x32_bf16(a, bh0, acc0, 0, 0, 0);
            acc0 = __builtin_amdgcn_mfma_f32_16x16x32_bf16(a, bl0, acc0, 0, 0, 0);
            acc1 = __builtin_amdgcn_mfma_f32_16x16x32_bf16(a, bh1, acc1, 0, 0, 0);
            acc1 = __builtin_amdgcn_mfma_f32_16x16x32_bf16(a, bl1, acc1, 0, 0, 0);
        }
    }

    // ---- epilogue: D[row = rt*16 + (lane>>4)*4 + r][h = ct*16 + lm] ----
    {
        const size_t stride = (size_t)NF * NHID;
        #pragma unroll
        for (int r = 0; r < 4; ++r) {
            const int row = rt * 16 + ((lane >> 4) << 2) + r;
            const float inv = invs[row];
            float* op = out + (size_t)(b0 + row) * stride + (size_t)f * NHID + lm;
            op[ct0 * 16]       = acc0[r] * inv;
            op[(ct0 + 1) * 16] = acc1[r] * inv;
        }
    }
}

// ---------------------------------------------------------------------------
extern "C" void kernel_launch(void* const* d_in, const int* in_sizes, int n_in,
                              void* d_out, int out_size, void* d_ws, size_t ws_size,
                              hipStream_t stream) {
    const float* O   = (const float*)d_in[0];
    const float* g1w = (const float*)d_in[1];
    const float* g1b = (const float*)d_in[2];
    const float* W1  = (const float*)d_in[3];
    const float* b1  = (const float*)d_in[4];
    const float* g2w = (const float*)d_in[5];
    const float* g2b = (const float*)d_in[6];
    const float* W2  = (const float*)d_in[7];
    const float* b2  = (const float*)d_in[8];
    const float* E   = (const float*)d_in[9];
    const int*   swr = (const int*)d_in[10];

    float*    wbuf = (float*)d_ws;                              // 256 KB
    unsigned* Esp  = (unsigned*)((char*)d_ws + 256 * 1024);     // 256 KB
    float*    out  = (float*)d_out;                             // [B, NF, NHID]

    phi2_kernel<<<dim3((BB * NRODT) / 256), 256, 0, stream>>>(
        O, g1w, g1b, W1, b1, g2w, g2b, W2, b2, E, wbuf, Esp);

    forest_mfma_kernel<<<dim3(NF, BB / BT), TPB, 0, stream>>>(wbuf, Esp, swr, out);
}

// Round 9
// 16.967 us; speedup vs baseline: 1.0001x; 1.0001x over previous
//
#include <hip/hip_runtime.h>

#define BB     128
#define CCH    2048
#define NRODT  512
#define NEST   128
#define NF     100
#define NHID   128
#define BT     32      // batch rows per forest block
#define TPB    512

typedef __attribute__((ext_vector_type(8))) short short8v;
typedef __attribute__((ext_vector_type(4))) float f32x4;

static __device__ __forceinline__ unsigned short f2bf(float x) {
    unsigned u = __float_as_uint(x);
    u += 0x7FFFu + ((u >> 16) & 1u);   // RNE
    return (unsigned short)(u >> 16);
}
static __device__ __forceinline__ float bf2f(unsigned short h) {
    return __uint_as_float(((unsigned)h) << 16);
}

// ---------------------------------------------------------------------------
// Kernel 1: (a) per-(b,g) phi_2 pipeline -> wbuf[g*BB+b] (transposed), and
// (b) one E element per thread converted to packed {hi,lo} bf16 (Esp).
// ---------------------------------------------------------------------------
__global__ __launch_bounds__(256) void phi2_kernel(
    const float* __restrict__ O,
    const float* __restrict__ g1w, const float* __restrict__ g1b,
    const float* __restrict__ W1,  const float* __restrict__ b1,
    const float* __restrict__ g2w, const float* __restrict__ g2b,
    const float* __restrict__ W2,  const float* __restrict__ b2,
    const float* __restrict__ E,
    float* __restrict__ wbuf,
    unsigned* __restrict__ Esp)
{
    const int t = blockIdx.x * 256 + threadIdx.x;
    const int b = t >> 9;
    const int g = t & (NRODT - 1);

    // ---- E hi/lo split: one element per thread (65536 == 512*128) ----
    {
        const float ex = E[t];
        const unsigned short xh = f2bf(ex);
        const float r = ex - bf2f(xh);
        const unsigned short xl = f2bf(r);
        Esp[t] = ((unsigned)xh) | (((unsigned)xl) << 16);
    }

    const float4 x = *reinterpret_cast<const float4*>(O + (size_t)b * CCH + g * 4);

    float m  = 0.25f * ((x.x + x.y) + (x.z + x.w));
    float d0 = x.x - m, d1 = x.y - m, d2 = x.z - m, d3 = x.w - m;
    float v  = 0.25f * ((d0 * d0 + d1 * d1) + (d2 * d2 + d3 * d3));
    float iv = rsqrtf(v + 1e-5f);
    const float4 gw1 = *reinterpret_cast<const float4*>(g1w + g * 4);
    const float4 gb1 = *reinterpret_cast<const float4*>(g1b + g * 4);
    float a0 = fmaf(d0 * iv, gw1.x, gb1.x);
    float a1 = fmaf(d1 * iv, gw1.y, gb1.y);
    float a2 = fmaf(d2 * iv, gw1.z, gb1.z);
    float a3 = fmaf(d3 * iv, gw1.w, gb1.w);

    const float4 r0 = *reinterpret_cast<const float4*>(W1 + g * 16 + 0);
    const float4 r1 = *reinterpret_cast<const float4*>(W1 + g * 16 + 4);
    const float4 r2 = *reinterpret_cast<const float4*>(W1 + g * 16 + 8);
    const float4 r3 = *reinterpret_cast<const float4*>(W1 + g * 16 + 12);
    const float4 bc = *reinterpret_cast<const float4*>(b1 + g * 4);
    float y0 = fmaf(a0, r0.x, fmaf(a1, r1.x, fmaf(a2, r2.x, fmaf(a3, r3.x, bc.x))));
    float y1 = fmaf(a0, r0.y, fmaf(a1, r1.y, fmaf(a2, r2.y, fmaf(a3, r3.y, bc.y))));
    float y2 = fmaf(a0, r0.z, fmaf(a1, r1.z, fmaf(a2, r2.z, fmaf(a3, r3.z, bc.z))));
    float y3 = fmaf(a0, r0.w, fmaf(a1, r1.w, fmaf(a2, r2.w, fmaf(a3, r3.w, bc.w))));
    y0 = fmaxf(y0, 0.f); y1 = fmaxf(y1, 0.f); y2 = fmaxf(y2, 0.f); y3 = fmaxf(y3, 0.f);

    m  = 0.25f * ((y0 + y1) + (y2 + y3));
    d0 = y0 - m; d1 = y1 - m; d2 = y2 - m; d3 = y3 - m;
    v  = 0.25f * ((d0 * d0 + d1 * d1) + (d2 * d2 + d3 * d3));
    iv = rsqrtf(v + 1e-5f);
    const float4 gw2 = *reinterpret_cast<const float4*>(g2w + g * 4);
    const float4 gb2 = *reinterpret_cast<const float4*>(g2b + g * 4);
    float z0 = fmaf(d0 * iv, gw2.x, gb2.x);
    float z1 = fmaf(d1 * iv, gw2.y, gb2.y);
    float z2 = fmaf(d2 * iv, gw2.z, gb2.z);
    float z3 = fmaf(d3 * iv, gw2.w, gb2.w);

    const float4 w2 = *reinterpret_cast<const float4*>(W2 + g * 4);
    float res = fmaf(z0, w2.x, fmaf(z1, w2.y, fmaf(z2, w2.z, fmaf(z3, w2.w, b2[g]))));

    wbuf[g * BB + b] = res;   // transposed [NRODT, B]
}

// ---------------------------------------------------------------------------
// Kernel 2: per (f, 32-batch tile). Coalesced wT gather -> softmax -> bf16 P;
// E staged from pre-split packed bf16 (no conversion VALU); MFMA combine.
// ---------------------------------------------------------------------------
__global__ __launch_bounds__(TPB) void forest_mfma_kernel(
    const float*    __restrict__ wv,    // [NRODT, B]  (transposed)
    const unsigned* __restrict__ Esp,   // [NRODT, NHID] packed {hi,lo} bf16
    const int*      __restrict__ swr,   // [NF, NEST]
    float* __restrict__ out)            // [B, NF, NHID]
{
    __shared__ __align__(16) short Prow[BT][136];   // P bf16, row stride 272B
    __shared__ __align__(16) char  pool[2 * 128 * 72 * 2];  // 36864B
    __shared__ int   ids[NEST];
    __shared__ float invs[BT];

    short (*Ehi)[72] = reinterpret_cast<short(*)[72]>(pool);
    short (*Elo)[72] = reinterpret_cast<short(*)[72]>(pool + 128 * 72 * 2);
    float (*wT)[36]  = reinterpret_cast<float(*)[36]>(pool);  // dead after softmax

    const int f   = blockIdx.x;
    const int b0  = blockIdx.y * BT;
    const int tid = threadIdx.x;

    if (tid < NEST) ids[tid] = swr[f * NEST + tid];
    __syncthreads();

    // ---- stage wT[e][b] coalesced: thread (e = tid>>2, j = tid&3) -> 8 b's ----
    {
        const int e = tid >> 2;
        const int j = tid & 3;
        const float* src = wv + (size_t)ids[e] * BB + b0 + (j << 3);
        const float4 va = *reinterpret_cast<const float4*>(src);
        const float4 vb = *reinterpret_cast<const float4*>(src + 4);
        *reinterpret_cast<float4*>(&wT[e][(j << 3) + 0]) = va;
        *reinterpret_cast<float4*>(&wT[e][(j << 3) + 4]) = vb;
    }
    __syncthreads();

    // ---- softmax numerators (f32 from LDS), written to Prow as bf16 ----
    {
        const int bl = tid >> 4;          // 0..31 batch row
        const int jj = tid & 15;
        float val[8];
        float mx = -3.4e38f;
        #pragma unroll
        for (int k = 0; k < 8; ++k) {
            val[k] = wT[jj + (k << 4)][bl];
            mx = fmaxf(mx, val[k]);
        }
        mx = fmaxf(mx, __shfl_xor(mx, 1));
        mx = fmaxf(mx, __shfl_xor(mx, 2));
        mx = fmaxf(mx, __shfl_xor(mx, 4));
        mx = fmaxf(mx, __shfl_xor(mx, 8));
        float sum = 0.f;
        #pragma unroll
        for (int k = 0; k < 8; ++k) {
            float ex = __expf(val[k] - mx);
            sum += ex;
            Prow[bl][jj + (k << 4)] = (short)f2bf(ex);
        }
        sum += __shfl_xor(sum, 1);
        sum += __shfl_xor(sum, 2);
        sum += __shfl_xor(sum, 4);
        sum += __shfl_xor(sum, 8);
        if (jj == 0) invs[bl] = 1.f / sum;
    }
    __syncthreads();   // wT reads done -> pool reusable; Prow/invs visible

    // ---- MFMA setup ----
    const int lane = tid & 63;
    const int wid  = tid >> 6;          // 0..7
    const int rt   = wid & 1;           // row-tile (batch)
    const int ct0  = (wid >> 1) << 1;   // col-tiles ct0, ct0+1 (h)
    const int lm   = lane & 15;
    const int lk   = (lane >> 4) << 3;  // k-offset within 32-wide K-block

    f32x4 acc0 = {0.f, 0.f, 0.f, 0.f};
    f32x4 acc1 = {0.f, 0.f, 0.f, 0.f};

    const int h  = tid & 127;           // staging: h column
    const int eg = tid >> 7;            // staging: 16-estimator subgroup

    #pragma unroll
    for (int hf = 0; hf < 2; ++hf) {
        // ---- stage 64 estimator rows of pre-split E, transposed [h][e] ----
        {
            short hbuf[16], lbuf[16];
            #pragma unroll
            for (int i = 0; i < 16; ++i) {
                const int row = ids[hf * 64 + eg * 16 + i];        // wave-uniform
                const unsigned v = Esp[(size_t)row * NHID + h];    // coalesced 256B
                hbuf[i] = (short)(v & 0xFFFFu);
                lbuf[i] = (short)(v >> 16);
            }
            if (hf == 1) __syncthreads();   // prior half's MFMA reads done
            *reinterpret_cast<short8v*>(&Ehi[h][eg * 16 + 0]) = *reinterpret_cast<short8v*>(&hbuf[0]);
            *reinterpret_cast<short8v*>(&Ehi[h][eg * 16 + 8]) = *reinterpret_cast<short8v*>(&hbuf[8]);
            *reinterpret_cast<short8v*>(&Elo[h][eg * 16 + 0]) = *reinterpret_cast<short8v*>(&lbuf[0]);
            *reinterpret_cast<short8v*>(&Elo[h][eg * 16 + 8]) = *reinterpret_cast<short8v*>(&lbuf[8]);
        }
        __syncthreads();

        // ---- 2 K-blocks of 32 within this half ----
        #pragma unroll
        for (int kbl = 0; kbl < 2; ++kbl) {
            const short8v a =
                *reinterpret_cast<const short8v*>(&Prow[rt * 16 + lm][(hf * 2 + kbl) * 32 + lk]);
            const short8v bh0 = *reinterpret_cast<const short8v*>(&Ehi[ct0 * 16 + lm][kbl * 32 + lk]);
            const short8v bl0 = *reinterpret_cast<const short8v*>(&Elo[ct0 * 16 + lm][kbl * 32 + lk]);
            const short8v bh1 = *reinterpret_cast<const short8v*>(&Ehi[(ct0 + 1) * 16 + lm][kbl * 32 + lk]);
            const short8v bl1 = *reinterpret_cast<const short8v*>(&Elo[(ct0 + 1) * 16 + lm][kbl * 32 + lk]);
            acc0 = __builtin_amdgcn_mfma_f32_16x16x32_bf16(a, bh0, acc0, 0, 0, 0);
            acc0 = __builtin_amdgcn_mfma_f32_16x16x32_bf16(a, bl0, acc0, 0, 0, 0);
            acc1 = __builtin_amdgcn_mfma_f32_16x16x32_bf16(a, bh1, acc1, 0, 0, 0);
            acc1 = __builtin_amdgcn_mfma_f32_16x16x32_bf16(a, bl1, acc1, 0, 0, 0);
        }
    }

    // ---- epilogue: D[row = rt*16 + (lane>>4)*4 + r][h = ct*16 + lm] ----
    {
        const size_t stride = (size_t)NF * NHID;
        #pragma unroll
        for (int r = 0; r < 4; ++r) {
            const int row = rt * 16 + ((lane >> 4) << 2) + r;
            const float inv = invs[row];
            float* op = out + (size_t)(b0 + row) * stride + (size_t)f * NHID + lm;
            op[ct0 * 16]       = acc0[r] * inv;
            op[(ct0 + 1) * 16] = acc1[r] * inv;
        }
    }
}

// ---------------------------------------------------------------------------
extern "C" void kernel_launch(void* const* d_in, const int* in_sizes, int n_in,
                              void* d_out, int out_size, void* d_ws, size_t ws_size,
                              hipStream_t stream) {
    const float* O   = (const float*)d_in[0];
    const float* g1w = (const float*)d_in[1];
    const float* g1b = (const float*)d_in[2];
    const float* W1  = (const float*)d_in[3];
    const float* b1  = (const float*)d_in[4];
    const float* g2w = (const float*)d_in[5];
    const float* g2b = (const float*)d_in[6];
    const float* W2  = (const float*)d_in[7];
    const float* b2  = (const float*)d_in[8];
    const float* E   = (const float*)d_in[9];
    const int*   swr = (const int*)d_in[10];

    float*    wbuf = (float*)d_ws;                              // 256 KB
    unsigned* Esp  = (unsigned*)((char*)d_ws + 256 * 1024);     // 256 KB
    float*    out  = (float*)d_out;                             // [B, NF, NHID]

    phi2_kernel<<<dim3((BB * NRODT) / 256), 256, 0, stream>>>(
        O, g1w, g1b, W1, b1, g2w, g2b, W2, b2, E, wbuf, Esp);

    forest_mfma_kernel<<<dim3(NF, BB / BT), TPB, 0, stream>>>(wbuf, Esp, swr, out);
}

// Round 10
// 16.915 us; speedup vs baseline: 1.0031x; 1.0030x over previous
//
#include <hip/hip_runtime.h>

#define BB     128
#define CCH    2048
#define NRODT  512
#define NEST   128
#define NF     100
#define NHID   128
#define BT     32      // batch rows per forest block
#define TPB    512

typedef __attribute__((ext_vector_type(8))) short short8v;
typedef __attribute__((ext_vector_type(4))) float f32x4;

static __device__ __forceinline__ unsigned short f2bf(float x) {
    unsigned u = __float_as_uint(x);
    u += 0x7FFFu + ((u >> 16) & 1u);   // RNE
    return (unsigned short)(u >> 16);
}
static __device__ __forceinline__ float bf2f(unsigned short h) {
    return __uint_as_float(((unsigned)h) << 16);
}

// ---------------------------------------------------------------------------
// Kernel 1: (a) per-(b,g) phi_2 pipeline -> wbuf[g*BB+b] (transposed), and
// (b) one E element per thread converted to packed {hi,lo} bf16 (Esp).
// ---------------------------------------------------------------------------
__global__ __launch_bounds__(256) void phi2_kernel(
    const float* __restrict__ O,
    const float* __restrict__ g1w, const float* __restrict__ g1b,
    const float* __restrict__ W1,  const float* __restrict__ b1,
    const float* __restrict__ g2w, const float* __restrict__ g2b,
    const float* __restrict__ W2,  const float* __restrict__ b2,
    const float* __restrict__ E,
    float* __restrict__ wbuf,
    unsigned* __restrict__ Esp)
{
    const int t = blockIdx.x * 256 + threadIdx.x;
    const int b = t >> 9;
    const int g = t & (NRODT - 1);

    // ---- E hi/lo split: one element per thread (65536 == 512*128) ----
    {
        const float ex = E[t];
        const unsigned short xh = f2bf(ex);
        const float r = ex - bf2f(xh);
        const unsigned short xl = f2bf(r);
        Esp[t] = ((unsigned)xh) | (((unsigned)xl) << 16);
    }

    const float4 x = *reinterpret_cast<const float4*>(O + (size_t)b * CCH + g * 4);

    float m  = 0.25f * ((x.x + x.y) + (x.z + x.w));
    float d0 = x.x - m, d1 = x.y - m, d2 = x.z - m, d3 = x.w - m;
    float v  = 0.25f * ((d0 * d0 + d1 * d1) + (d2 * d2 + d3 * d3));
    float iv = rsqrtf(v + 1e-5f);
    const float4 gw1 = *reinterpret_cast<const float4*>(g1w + g * 4);
    const float4 gb1 = *reinterpret_cast<const float4*>(g1b + g * 4);
    float a0 = fmaf(d0 * iv, gw1.x, gb1.x);
    float a1 = fmaf(d1 * iv, gw1.y, gb1.y);
    float a2 = fmaf(d2 * iv, gw1.z, gb1.z);
    float a3 = fmaf(d3 * iv, gw1.w, gb1.w);

    const float4 r0 = *reinterpret_cast<const float4*>(W1 + g * 16 + 0);
    const float4 r1 = *reinterpret_cast<const float4*>(W1 + g * 16 + 4);
    const float4 r2 = *reinterpret_cast<const float4*>(W1 + g * 16 + 8);
    const float4 r3 = *reinterpret_cast<const float4*>(W1 + g * 16 + 12);
    const float4 bc = *reinterpret_cast<const float4*>(b1 + g * 4);
    float y0 = fmaf(a0, r0.x, fmaf(a1, r1.x, fmaf(a2, r2.x, fmaf(a3, r3.x, bc.x))));
    float y1 = fmaf(a0, r0.y, fmaf(a1, r1.y, fmaf(a2, r2.y, fmaf(a3, r3.y, bc.y))));
    float y2 = fmaf(a0, r0.z, fmaf(a1, r1.z, fmaf(a2, r2.z, fmaf(a3, r3.z, bc.z))));
    float y3 = fmaf(a0, r0.w, fmaf(a1, r1.w, fmaf(a2, r2.w, fmaf(a3, r3.w, bc.w))));
    y0 = fmaxf(y0, 0.f); y1 = fmaxf(y1, 0.f); y2 = fmaxf(y2, 0.f); y3 = fmaxf(y3, 0.f);

    m  = 0.25f * ((y0 + y1) + (y2 + y3));
    d0 = y0 - m; d1 = y1 - m; d2 = y2 - m; d3 = y3 - m;
    v  = 0.25f * ((d0 * d0 + d1 * d1) + (d2 * d2 + d3 * d3));
    iv = rsqrtf(v + 1e-5f);
    const float4 gw2 = *reinterpret_cast<const float4*>(g2w + g * 4);
    const float4 gb2 = *reinterpret_cast<const float4*>(g2b + g * 4);
    float z0 = fmaf(d0 * iv, gw2.x, gb2.x);
    float z1 = fmaf(d1 * iv, gw2.y, gb2.y);
    float z2 = fmaf(d2 * iv, gw2.z, gb2.z);
    float z3 = fmaf(d3 * iv, gw2.w, gb2.w);

    const float4 w2 = *reinterpret_cast<const float4*>(W2 + g * 4);
    float res = fmaf(z0, w2.x, fmaf(z1, w2.y, fmaf(z2, w2.z, fmaf(z3, w2.w, b2[g]))));

    wbuf[g * BB + b] = res;   // transposed [NRODT, B]
}

// ---------------------------------------------------------------------------
// Kernel 2: per (f, 32-batch tile). Coalesced wT gather -> softmax -> bf16 P;
// E staged from pre-split packed bf16 (no conversion VALU); MFMA combine.
// ---------------------------------------------------------------------------
__global__ __launch_bounds__(TPB) void forest_mfma_kernel(
    const float*    __restrict__ wv,    // [NRODT, B]  (transposed)
    const unsigned* __restrict__ Esp,   // [NRODT, NHID] packed {hi,lo} bf16
    const int*      __restrict__ swr,   // [NF, NEST]
    float* __restrict__ out)            // [B, NF, NHID]
{
    __shared__ __align__(16) short Prow[BT][136];   // P bf16, row stride 272B
    __shared__ __align__(16) char  pool[2 * 128 * 72 * 2];  // 36864B
    __shared__ int   ids[NEST];
    __shared__ float invs[BT];

    short (*Ehi)[72] = reinterpret_cast<short(*)[72]>(pool);
    short (*Elo)[72] = reinterpret_cast<short(*)[72]>(pool + 128 * 72 * 2);
    float (*wT)[36]  = reinterpret_cast<float(*)[36]>(pool);  // dead after softmax

    const int f   = blockIdx.x;
    const int b0  = blockIdx.y * BT;
    const int tid = threadIdx.x;

    if (tid < NEST) ids[tid] = swr[f * NEST + tid];
    __syncthreads();

    // ---- stage wT[e][b] coalesced: thread (e = tid>>2, j = tid&3) -> 8 b's ----
    {
        const int e = tid >> 2;
        const int j = tid & 3;
        const float* src = wv + (size_t)ids[e] * BB + b0 + (j << 3);
        const float4 va = *reinterpret_cast<const float4*>(src);
        const float4 vb = *reinterpret_cast<const float4*>(src + 4);
        *reinterpret_cast<float4*>(&wT[e][(j << 3) + 0]) = va;
        *reinterpret_cast<float4*>(&wT[e][(j << 3) + 4]) = vb;
    }
    __syncthreads();

    // ---- softmax numerators (f32 from LDS), written to Prow as bf16 ----
    {
        const int bl = tid >> 4;          // 0..31 batch row
        const int jj = tid & 15;
        float val[8];
        float mx = -3.4e38f;
        #pragma unroll
        for (int k = 0; k < 8; ++k) {
            val[k] = wT[jj + (k << 4)][bl];
            mx = fmaxf(mx, val[k]);
        }
        mx = fmaxf(mx, __shfl_xor(mx, 1));
        mx = fmaxf(mx, __shfl_xor(mx, 2));
        mx = fmaxf(mx, __shfl_xor(mx, 4));
        mx = fmaxf(mx, __shfl_xor(mx, 8));
        float sum = 0.f;
        #pragma unroll
        for (int k = 0; k < 8; ++k) {
            float ex = __expf(val[k] - mx);
            sum += ex;
            Prow[bl][jj + (k << 4)] = (short)f2bf(ex);
        }
        sum += __shfl_xor(sum, 1);
        sum += __shfl_xor(sum, 2);
        sum += __shfl_xor(sum, 4);
        sum += __shfl_xor(sum, 8);
        if (jj == 0) invs[bl] = 1.f / sum;
    }
    __syncthreads();   // wT reads done -> pool reusable; Prow/invs visible

    // ---- MFMA setup ----
    const int lane = tid & 63;
    const int wid  = tid >> 6;          // 0..7
    const int rt   = wid & 1;           // row-tile (batch)
    const int ct0  = (wid >> 1) << 1;   // col-tiles ct0, ct0+1 (h)
    const int lm   = lane & 15;
    const int lk   = (lane >> 4) << 3;  // k-offset within 32-wide K-block

    f32x4 acc0 = {0.f, 0.f, 0.f, 0.f};
    f32x4 acc1 = {0.f, 0.f, 0.f, 0.f};

    const int h  = tid & 127;           // staging: h column
    const int eg = tid >> 7;            // staging: 16-estimator subgroup

    #pragma unroll
    for (int hf = 0; hf < 2; ++hf) {
        // ---- stage 64 estimator rows of pre-split E, transposed [h][e] ----
        {
            short hbuf[16], lbuf[16];
            #pragma unroll
            for (int i = 0; i < 16; ++i) {
                const int row = ids[hf * 64 + eg * 16 + i];        // wave-uniform
                const unsigned v = Esp[(size_t)row * NHID + h];    // coalesced 256B
                hbuf[i] = (short)(v & 0xFFFFu);
                lbuf[i] = (short)(v >> 16);
            }
            if (hf == 1) __syncthreads();   // prior half's MFMA reads done
            *reinterpret_cast<short8v*>(&Ehi[h][eg * 16 + 0]) = *reinterpret_cast<short8v*>(&hbuf[0]);
            *reinterpret_cast<short8v*>(&Ehi[h][eg * 16 + 8]) = *reinterpret_cast<short8v*>(&hbuf[8]);
            *reinterpret_cast<short8v*>(&Elo[h][eg * 16 + 0]) = *reinterpret_cast<short8v*>(&lbuf[0]);
            *reinterpret_cast<short8v*>(&Elo[h][eg * 16 + 8]) = *reinterpret_cast<short8v*>(&lbuf[8]);
        }
        __syncthreads();

        // ---- 2 K-blocks of 32 within this half ----
        #pragma unroll
        for (int kbl = 0; kbl < 2; ++kbl) {
            const short8v a =
                *reinterpret_cast<const short8v*>(&Prow[rt * 16 + lm][(hf * 2 + kbl) * 32 + lk]);
            const short8v bh0 = *reinterpret_cast<const short8v*>(&Ehi[ct0 * 16 + lm][kbl * 32 + lk]);
            const short8v bl0 = *reinterpret_cast<const short8v*>(&Elo[ct0 * 16 + lm][kbl * 32 + lk]);
            const short8v bh1 = *reinterpret_cast<const short8v*>(&Ehi[(ct0 + 1) * 16 + lm][kbl * 32 + lk]);
            const short8v bl1 = *reinterpret_cast<const short8v*>(&Elo[(ct0 + 1) * 16 + lm][kbl * 32 + lk]);
            acc0 = __builtin_amdgcn_mfma_f32_16x16x32_bf16(a, bh0, acc0, 0, 0, 0);
            acc0 = __builtin_amdgcn_mfma_f32_16x16x32_bf16(a, bl0, acc0, 0, 0, 0);
            acc1 = __builtin_amdgcn_mfma_f32_16x16x32_bf16(a, bh1, acc1, 0, 0, 0);
            acc1 = __builtin_amdgcn_mfma_f32_16x16x32_bf16(a, bl1, acc1, 0, 0, 0);
        }
    }

    // ---- epilogue: D[row = rt*16 + (lane>>4)*4 + r][h = ct*16 + lm] ----
    {
        const size_t stride = (size_t)NF * NHID;
        #pragma unroll
        for (int r = 0; r < 4; ++r) {
            const int row = rt * 16 + ((lane >> 4) << 2) + r;
            const float inv = invs[row];
            float* op = out + (size_t)(b0 + row) * stride + (size_t)f * NHID + lm;
            op[ct0 * 16]       = acc0[r] * inv;
            op[(ct0 + 1) * 16] = acc1[r] * inv;
        }
    }
}

// ---------------------------------------------------------------------------
extern "C" void kernel_launch(void* const* d_in, const int* in_sizes, int n_in,
                              void* d_out, int out_size, void* d_ws, size_t ws_size,
                              hipStream_t stream) {
    const float* O   = (const float*)d_in[0];
    const float* g1w = (const float*)d_in[1];
    const float* g1b = (const float*)d_in[2];
    const float* W1  = (const float*)d_in[3];
    const float* b1  = (const float*)d_in[4];
    const float* g2w = (const float*)d_in[5];
    const float* g2b = (const float*)d_in[6];
    const float* W2  = (const float*)d_in[7];
    const float* b2  = (const float*)d_in[8];
    const float* E   = (const float*)d_in[9];
    const int*   swr = (const int*)d_in[10];

    float*    wbuf = (float*)d_ws;                              // 256 KB
    unsigned* Esp  = (unsigned*)((char*)d_ws + 256 * 1024);     // 256 KB
    float*    out  = (float*)d_out;                             // [B, NF, NHID]

    phi2_kernel<<<dim3((BB * NRODT) / 256), 256, 0, stream>>>(
        O, g1w, g1b, W1, b1, g2w, g2b, W2, b2, E, wbuf, Esp);

    forest_mfma_kernel<<<dim3(NF, BB / BT), TPB, 0, stream>>>(wbuf, Esp, swr, out);
}